// Round 1
// baseline (123.304 us; speedup 1.0000x reference)
//
#include <hip/hip_runtime.h>
#include <math.h>

// Second-order IIR (B=1024 rows, T=16384), fp32.
// One row per block; row processed in two 8192-element halves.
// Per half: stage->LDS (padded), per-thread zero-state chunk pass (CK=32,
// v kept in VGPRs), wave-0 Kogge-Stone affine scan over 256 chunk states,
// per-thread fixup pass writing y into LDS, coalesced float4 drain.

#define TLEN     16384
#define HALF     8192
#define NT       256
#define CK       32                      // elements per thread per half
#define NCH      256                     // chunks per half (== NT)
// padded u buffer: addr(i) = i + ((i+30)>>5); max ext index = HALF+1 = 8193
// addr(8193) = 8193 + 256 = 8449  -> size 8450
#define SCAN_OFF   8450
#define CARRY_OFF  (SCAN_OFF + 2*NCH)    // 8962
#define LDS_FLOATS (CARRY_OFF + 2)       // 8964 floats = 35856 B (<64KB static)

__device__ __forceinline__ void mat2_sq(float& m00, float& m01, float& m10, float& m11) {
    float t00 = m00*m00 + m01*m10;
    float t01 = m00*m01 + m01*m11;
    float t10 = m10*m00 + m11*m10;
    float t11 = m10*m01 + m11*m11;
    m00 = t00; m01 = t01; m10 = t10; m11 = t11;
}

__global__ __launch_bounds__(NT, 4)
void iir_kernel(const float* __restrict__ bc,
                const float* __restrict__ rho_p,
                const float* __restrict__ psi_p,
                const float* __restrict__ u_in,
                const float* __restrict__ y_init,
                const float* __restrict__ u_init,
                float* __restrict__ y_out)
{
    __shared__ float lds[LDS_FLOATS];
    const int row = blockIdx.x;
    const int tid = threadIdx.x;

    // scalar filter parameters (cheap, per-thread)
    const float rho = rho_p[0];
    const float psi = psi_p[0];
    const float r   = 1.0f / (1.0f + expf(-rho));
    const float th  = 3.14159265358979323846f / (1.0f + expf(-psi)); // pi*sigmoid(psi)
    const float a1  = -2.0f * r * cosf(th);
    const float a2  = r * r;
    const float b0  = bc[0], b1 = bc[1], b2 = bc[2];

    const float* urow = u_in  + (size_t)row * TLEN;
    float*       orow = y_out + (size_t)row * TLEN;

    for (int h = 0; h < 2; ++h) {
        const float* uh = urow + h * HALF;

        // ---- stage half into LDS (pad every 32 floats; write pattern 2 lanes/bank) ----
        #pragma unroll
        for (int k = 0; k < 8; ++k) {
            int g = tid + k * NT;
            float4 uv = ((const float4*)uh)[g];
            int base = 4*g + 3 + (g >> 3);      // addr(4g+2): pad uniform across the 4 floats
            lds[base + 0] = uv.x;
            lds[base + 1] = uv.y;
            lds[base + 2] = uv.z;
            lds[base + 3] = uv.w;
        }
        if (tid == 0) {
            // u_ext[0] = u_init[:,1], u_ext[1] = u_init[:,0] for half 0;
            // last two u's of previous half otherwise. addr(0)=0, addr(1)=1.
            lds[0] = (h == 0) ? u_init[2*row + 1] : urow[h*HALF - 2];
            lds[1] = (h == 0) ? u_init[2*row + 0] : urow[h*HALF - 1];
        }
        __syncthreads();

        // ---- pass 1: zero-state chunk response, v cached in VGPRs ----
        const int ub = 33 * tid;                // addr(32*tid)
        float um2 = lds[ub];
        float um1 = lds[ub + 1];
        float v[CK];
        float y1 = 0.0f, y2 = 0.0f;
        #pragma unroll
        for (int j = 0; j < CK; ++j) {
            float uc = lds[ub + 3 + j];         // addr(32*tid + 2 + j) = 33*tid + 3 + j
            float vv = fmaf(b2, um2, fmaf(b1, um1, b0 * uc));
            v[j] = vv;
            float y = fmaf(-a1, y1, fmaf(-a2, y2, vv));
            y2 = y1; y1 = y;
            um2 = um1; um1 = uc;
        }
        lds[SCAN_OFF + 2*tid]     = y1;         // chunk d = (y[last], y[last-1])
        lds[SCAN_OFF + 2*tid + 1] = y2;
        __syncthreads();

        // ---- wave-0 affine scan over 256 chunk states ----
        if (tid < 64) {
            const int l = tid;
            // M = A^CK = A^32 via 5 squarings; A = [[-a1,-a2],[1,0]]
            float m00 = -a1, m01 = -a2, m10 = 1.0f, m11 = 0.0f;
            #pragma unroll
            for (int s = 0; s < 5; ++s) mat2_sq(m00, m01, m10, m11);

            float da[4], db[4];
            #pragma unroll
            for (int m = 0; m < 4; ++m) {
                da[m] = lds[SCAN_OFF + 8*l + 2*m];
                db[m] = lds[SCAN_OFF + 8*l + 2*m + 1];
            }

            float seed0 = 0.0f, seed1 = 0.0f;
            if (l == 0) {
                if (h == 0) { seed0 = y_init[2*row]; seed1 = y_init[2*row + 1]; }
                else        { seed0 = lds[CARRY_OFF]; seed1 = lds[CARRY_OFF + 1]; }
            }
            // serial fold of this lane's 4 chunks (lane 0 seeded with s_{-1})
            float s0 = seed0, s1 = seed1;
            #pragma unroll
            for (int m = 0; m < 4; ++m) {
                float n0 = fmaf(m00, s0, fmaf(m01, s1, da[m]));
                float n1 = fmaf(m10, s0, fmaf(m11, s1, db[m]));
                s0 = n0; s1 = n1;
            }
            // W = M^4; Kogge-Stone inclusive scan over 64 lanes
            float w00 = m00, w01 = m01, w10 = m10, w11 = m11;
            mat2_sq(w00, w01, w10, w11);
            mat2_sq(w00, w01, w10, w11);
            #pragma unroll
            for (int p = 0; p < 6; ++p) {
                float o0 = __shfl_up(s0, 1 << p);
                float o1 = __shfl_up(s1, 1 << p);
                if (l >= (1 << p)) {
                    s0 = fmaf(w00, o0, fmaf(w01, o1, s0));
                    s1 = fmaf(w10, o0, fmaf(w11, o1, s1));
                }
                if (p < 5) mat2_sq(w00, w01, w10, w11);
            }
            // incoming state for chunk 4l = prefix of lane l-1 (or seed for l=0)
            float p0 = __shfl_up(s0, 1);
            float p1 = __shfl_up(s1, 1);
            if (l == 0) { p0 = seed0; p1 = seed1; }
            float c0 = p0, c1 = p1;
            #pragma unroll
            for (int m = 0; m < 4; ++m) {
                lds[SCAN_OFF + 2*(4*l + m)]     = c0;
                lds[SCAN_OFF + 2*(4*l + m) + 1] = c1;
                float n0 = fmaf(m00, c0, fmaf(m01, c1, da[m]));
                float n1 = fmaf(m10, c0, fmaf(m11, c1, db[m]));
                c0 = n0; c1 = n1;
            }
        }
        __syncthreads();

        // ---- final pass: exact recurrence from the correct incoming state ----
        float y1f = lds[SCAN_OFF + 2*tid];      // y[chunk_start-1]
        float y2f = lds[SCAN_OFF + 2*tid + 1];  // y[chunk_start-2]
        #pragma unroll
        for (int j = 0; j < CK; ++j) {
            float y = fmaf(-a1, y1f, fmaf(-a2, y2f, v[j]));
            lds[ub + 3 + j] = y;                // overwrite u slot (safe: all u reads done)
            y2f = y1f; y1f = y;
        }
        if (tid == NT - 1) {                    // exact carry into next half
            lds[CARRY_OFF]     = y1f;
            lds[CARRY_OFF + 1] = y2f;
        }
        __syncthreads();

        // ---- drain: LDS -> global, coalesced float4 ----
        float* oh = orow + h * HALF;
        #pragma unroll
        for (int k = 0; k < 8; ++k) {
            int g = tid + k * NT;
            int base = 4*g + 3 + (g >> 3);
            float4 ov;
            ov.x = lds[base + 0];
            ov.y = lds[base + 1];
            ov.z = lds[base + 2];
            ov.w = lds[base + 3];
            ((float4*)oh)[g] = ov;
        }
        __syncthreads();                        // protect LDS before next half's staging
    }
}

extern "C" void kernel_launch(void* const* d_in, const int* in_sizes, int n_in,
                              void* d_out, int out_size, void* d_ws, size_t ws_size,
                              hipStream_t stream) {
    const float* bc    = (const float*)d_in[0];
    const float* rho   = (const float*)d_in[1];
    const float* psi   = (const float*)d_in[2];
    const float* u_in  = (const float*)d_in[3];
    const float* y_in  = (const float*)d_in[4];
    const float* u_ini = (const float*)d_in[5];
    float* y = (float*)d_out;
    const int B = in_sizes[3] / TLEN;           // 1024
    iir_kernel<<<B, NT, 0, stream>>>(bc, rho, psi, u_in, y_in, u_ini, y);
}